// Round 1
// baseline (2190.756 us; speedup 1.0000x reference)
//
#include <hip/hip_runtime.h>
#include <stdint.h>

#define T_STEPS 256
#define EMBD 10
#define MB 16          // batch rows per block
#define NBLK 64        // 1024 / MB
#define NKIT 9         // K = 288 = 9 * 32 (256 h + 10 x + 1 bias + pad)

typedef __attribute__((ext_vector_type(8))) short bf16x8;
typedef __attribute__((ext_vector_type(4))) float f32x4;

__device__ __forceinline__ unsigned short f2bf(float f) {
    union { float f; unsigned int u; } v; v.f = f;
    unsigned int u = v.u;
    unsigned int r = (u + 0x7FFFu + ((u >> 16) & 1u)) >> 16;  // RNE
    return (unsigned short)r;
}

__device__ __forceinline__ float sig_fast(float x) {
    // 1/(1+2^(-x*log2e)); safe at +-inf (rcp(inf)=0)
    return __frcp_rn(1.0f + exp2f(-1.4426950408889634f * x));
}
__device__ __forceinline__ float tanh_fast(float x) {
    // 1 - 2/(2^(2x*log2e)+1); safe at +-inf
    return 1.0f - 2.0f * __frcp_rn(exp2f(2.8853900817779268f * x) + 1.0f);
}

// ---------------------------------------------------------------------------
// K1: build swizzled bf16 weight matrix Wfull[288][1024] in MFMA B-frag order.
// Layout: [ntile 0..63][kit 0..8][lane 0..63] x 16B, where the lane's 8 bf16
// are Wfull[k = kit*32 + (lane>>4)*8 + j][n = ntile*16 + (lane&15)], j=0..7.
// Rows: k<256 -> Wh[k][:], 256..265 -> Wx[k-256][:], 266 -> bias, else 0.
// Column n: gate q = n>>8 (g,i,f,o), col = n&255.
// ---------------------------------------------------------------------------
__global__ __launch_bounds__(64) void build_wswz(
    const float* __restrict__ Wgx, const float* __restrict__ Wgh, const float* __restrict__ bg,
    const float* __restrict__ Wix, const float* __restrict__ Wih, const float* __restrict__ bi,
    const float* __restrict__ Wfx, const float* __restrict__ Wfh, const float* __restrict__ bf_,
    const float* __restrict__ Wox, const float* __restrict__ Woh, const float* __restrict__ bo,
    unsigned short* __restrict__ wswz)
{
    int g   = blockIdx.x / NKIT;   // ntile
    int kit = blockIdx.x % NKIT;
    int lane = threadIdx.x;
    int n = g * 16 + (lane & 15);
    int q = n >> 8;
    int col = n & 255;
    const float* Wh = (q == 0) ? Wgh : (q == 1) ? Wih : (q == 2) ? Wfh : Woh;
    const float* Wx = (q == 0) ? Wgx : (q == 1) ? Wix : (q == 2) ? Wfx : Wox;
    const float* bb = (q == 0) ? bg  : (q == 1) ? bi  : (q == 2) ? bf_ : bo;
    int k0 = kit * 32 + (lane >> 4) * 8;

    int4 out;
    unsigned short* p = (unsigned short*)&out;
#pragma unroll
    for (int j = 0; j < 8; j++) {
        int k = k0 + j;
        float v = 0.0f;
        if (k < 256)            v = Wh[k * 256 + col];
        else if (k < 256 + EMBD) v = Wx[(k - 256) * 256 + col];
        else if (k == 266)      v = bb[col];
        p[j] = f2bf(v);
    }
    ((int4*)wswz)[blockIdx.x * 64 + lane] = out;
}

// ---------------------------------------------------------------------------
// K2: persistent LSTM. 64 blocks x 512 threads (8 waves). Block owns 16 batch
// rows. Wave w owns h-columns [w*32, w*32+32) across all 4 gates (8 N-tiles).
// A-tile (16 x 288 bf16) lives in LDS in MFMA A-frag order, rebuilt per step.
// c kept fp32 in registers. No inter-block communication.
// ---------------------------------------------------------------------------
__global__ __launch_bounds__(512, 2) void lstm_main(
    const int*   __restrict__ xtok,   // [1024][1][256]
    const float* __restrict__ emb,    // [32000][10]
    const float* __restrict__ Wph,    // [256][10]
    const float* __restrict__ bp,     // [10]
    const unsigned short* __restrict__ wswz,
    float* __restrict__ out)          // [1024][10]
{
    __shared__ __align__(16) unsigned short A_lds[NKIT * 64 * 8];  // 9 KB
    __shared__ float outacc[MB * 10];

    const int tid  = threadIdx.x;
    const int w    = tid >> 6;        // wave 0..7
    const int lane = tid & 63;
    const int quad = lane >> 4;
    const int l15  = lane & 15;
    const int blk  = blockIdx.x;

    const int m_x = tid >> 4;         // for x-gather: batch row 0..15 (tid<256)
    const int e_x = tid & 15;         // emb element (valid if <10)

    // --- init A-tile: zero, bias-const row (k=266 -> 1.0), x_0 rows ---
    for (int idx = tid; idx < NKIT * 64 * 8; idx += 512) A_lds[idx] = 0;
    __syncthreads();
    if (tid < 16) {
        // k=266: kiter=8, lane' = m+16, j=2
        A_lds[(8 * 64 + 16 + tid) * 8 + 2] = 0x3F80;  // bf16(1.0)
    }
    if (tid < 256 && e_x < EMBD) {
        int tok = xtok[(blk * MB + m_x) * T_STEPS + 0];
        float v = emb[tok * EMBD + e_x];
        int k = 256 + e_x;
        int lp = m_x + 16 * ((k >> 3) & 3);
        A_lds[((k >> 5) * 64 + lp) * 8 + (k & 7)] = f2bf(v);
    }
    __syncthreads();

    float c[2][4], hreg[2][4];
#pragma unroll
    for (int u = 0; u < 2; u++)
#pragma unroll
        for (int r = 0; r < 4; r++) { c[u][r] = 0.0f; hreg[u][r] = 0.0f; }

    const int4* B    = (const int4*)wswz;
    const int4* Ald4 = (const int4*)A_lds;

    for (int t = 0; t < T_STEPS; t++) {
        // prefetch next step's x (independent of everything; hidden by MFMA)
        float xval = 0.0f;
        const int do_x = (t < T_STEPS - 1) && (tid < 256) && (e_x < EMBD);
        if ((t < T_STEPS - 1) && (tid < 256)) {
            int tok = xtok[(blk * MB + m_x) * T_STEPS + (t + 1)];
            if (e_x < EMBD) xval = emb[tok * EMBD + e_x];
        }

        // A-frags for this step (9 x ds_read_b128, contiguous per lane)
        int4 a[NKIT];
#pragma unroll
        for (int kit = 0; kit < NKIT; kit++) a[kit] = Ald4[kit * 64 + lane];
        __syncthreads();  // B1: everyone has A(t) in regs before anyone writes A(t+1)

        f32x4 acc[8];
#pragma unroll
        for (int i = 0; i < 8; i++) acc[i] = (f32x4){0.f, 0.f, 0.f, 0.f};

        // double-buffered B-fragment stream, global(L2)->VGPR, MFMA per N-tile
        int4 bb[2][NKIT];
        {
            int nt0 = 0 * 16 + w * 2 + 0;  // idx 0: gate 0, u 0
#pragma unroll
            for (int kit = 0; kit < NKIT; kit++)
                bb[0][kit] = B[(nt0 * NKIT + kit) * 64 + lane];
        }
#pragma unroll
        for (int idx = 0; idx < 8; idx++) {
            if (idx < 7) {
                int g2 = (idx + 1) >> 1, u2 = (idx + 1) & 1;
                int nt = g2 * 16 + w * 2 + u2;
#pragma unroll
                for (int kit = 0; kit < NKIT; kit++)
                    bb[(idx + 1) & 1][kit] = B[(nt * NKIT + kit) * 64 + lane];
            }
#pragma unroll
            for (int kit = 0; kit < NKIT; kit++) {
                acc[idx] = __builtin_amdgcn_mfma_f32_16x16x32_bf16(
                    __builtin_bit_cast(bf16x8, a[kit]),
                    __builtin_bit_cast(bf16x8, bb[idx & 1][kit]),
                    acc[idx], 0, 0, 0);
            }
        }

        // gates: all 4 gate values for (m,hcol) are in this lane, same reg r.
        // z[m][n]: m = quad*4 + r, n = (gate*256) + w*32 + u*16 + l15
#pragma unroll
        for (int u = 0; u < 2; u++) {
#pragma unroll
            for (int r = 0; r < 4; r++) {
                float zg = acc[0 * 2 + u][r];
                float zi = acc[1 * 2 + u][r];
                float zf = acc[2 * 2 + u][r];
                float zo = acc[3 * 2 + u][r];
                float gg = tanh_fast(zg);
                float ii = sig_fast(zi);
                float ff = sig_fast(zf);
                float oo = sig_fast(zo);
                float cn = gg * ii + c[u][r] * ff;
                c[u][r] = cn;
                float hh = tanh_fast(cn) * oo;
                hreg[u][r] = hh;
                // write h(t+1) into A-frag slot (k = hcol, kiter = w)
                int m = quad * 4 + r;
                int hcol = w * 32 + u * 16 + l15;
                int lp = m + 16 * ((hcol >> 3) & 3);
                A_lds[(w * 64 + lp) * 8 + (hcol & 7)] = f2bf(hh);
            }
        }
        if (do_x) {
            int k = 256 + e_x;
            int lp = m_x + 16 * ((k >> 3) & 3);
            A_lds[(8 * 64 + lp) * 8 + (k & 7)] = f2bf(xval);
        }
        __syncthreads();  // B2: A(t+1) complete
    }

    // --- epilogue: out[m][cls] = sum_hcol h[m][hcol]*Wph[hcol][cls] + bp ---
    float part[4][10];
#pragma unroll
    for (int r = 0; r < 4; r++)
#pragma unroll
        for (int cl = 0; cl < 10; cl++) part[r][cl] = 0.0f;
#pragma unroll
    for (int u = 0; u < 2; u++) {
        int hcol = w * 32 + u * 16 + l15;
#pragma unroll
        for (int cl = 0; cl < 10; cl++) {
            float wv = Wph[hcol * 10 + cl];
#pragma unroll
            for (int r = 0; r < 4; r++) part[r][cl] += hreg[u][r] * wv;
        }
    }
    // reduce across the 16 lanes of each quad (xor bits 0..3 stay in-quad)
#pragma unroll
    for (int off = 1; off < 16; off <<= 1) {
#pragma unroll
        for (int r = 0; r < 4; r++)
#pragma unroll
            for (int cl = 0; cl < 10; cl++)
                part[r][cl] += __shfl_xor(part[r][cl], off, 64);
    }
    if (tid < MB * 10) outacc[tid] = 0.0f;
    __syncthreads();
    if (l15 == 0) {
#pragma unroll
        for (int r = 0; r < 4; r++) {
            int m = quad * 4 + r;
#pragma unroll
            for (int cl = 0; cl < 10; cl++)
                atomicAdd(&outacc[m * 10 + cl], part[r][cl]);
        }
    }
    __syncthreads();
    if (tid < MB * 10) {
        int m = tid / 10, cl = tid - m * 10;
        out[(blk * MB + m) * 10 + cl] = outacc[tid] + bp[cl];
    }
}

extern "C" void kernel_launch(void* const* d_in, const int* in_sizes, int n_in,
                              void* d_out, int out_size, void* d_ws, size_t ws_size,
                              hipStream_t stream) {
    const int*   x    = (const int*)  d_in[0];
    const float* emb  = (const float*)d_in[1];
    const float* Wgx  = (const float*)d_in[2];
    const float* Wgh  = (const float*)d_in[3];
    const float* bg   = (const float*)d_in[4];
    const float* Wix  = (const float*)d_in[5];
    const float* Wih  = (const float*)d_in[6];
    const float* bi   = (const float*)d_in[7];
    const float* Wfx  = (const float*)d_in[8];
    const float* Wfh  = (const float*)d_in[9];
    const float* bf_  = (const float*)d_in[10];
    const float* Wox  = (const float*)d_in[11];
    const float* Woh  = (const float*)d_in[12];
    const float* bo   = (const float*)d_in[13];
    const float* Wph  = (const float*)d_in[14];
    const float* bp   = (const float*)d_in[15];

    unsigned short* wswz = (unsigned short*)d_ws;  // 64*9*64*16 = 576 KB

    build_wswz<<<NBLK * NKIT, 64, 0, stream>>>(Wgx, Wgh, bg, Wix, Wih, bi,
                                               Wfx, Wfh, bf_, Wox, Woh, bo, wswz);
    lstm_main<<<NBLK, 512, 0, stream>>>(x, emb, Wph, bp, wswz, (float*)d_out);
}

// Round 2
// 1733.939 us; speedup vs baseline: 1.2635x; 1.2635x over previous
//
#include <hip/hip_runtime.h>
#include <stdint.h>

#define T_STEPS 256
#define EMBD 10
#define MB 16          // batch rows per block
#define NBLK 64        // 1024 / MB
#define NKIT 9         // K = 288 = 9 * 32 (256 h + 10 x + 1 bias + pad)

typedef __attribute__((ext_vector_type(8))) short bf16x8;
typedef __attribute__((ext_vector_type(4))) float f32x4;

__device__ __forceinline__ unsigned short f2bf(float f) {
    union { float f; unsigned int u; } v; v.f = f;
    unsigned int u = v.u;
    unsigned int r = (u + 0x7FFFu + ((u >> 16) & 1u)) >> 16;  // RNE
    return (unsigned short)r;
}

__device__ __forceinline__ float sig_fast(float x) {
    return __frcp_rn(1.0f + exp2f(-1.4426950408889634f * x));
}
__device__ __forceinline__ float tanh_fast(float x) {
    return 1.0f - 2.0f * __frcp_rn(exp2f(2.8853900817779268f * x) + 1.0f);
}

// ---------------------------------------------------------------------------
// K1: build swizzled bf16 weight matrix Wfull[288][1024] in MFMA B-frag order.
// NEW layout: [kit 0..8][ntile 0..63][lane 0..63] x 16B  (kit-major so the
// LDS-resident kits 4,5 are one contiguous 128 KB slab).
// Lane's 8 bf16: Wfull[k = kit*32 + (lane>>4)*8 + j][n = ntile*16 + (lane&15)]
// Rows: k<256 -> Wh[k][:], 256..265 -> Wx[k-256][:], 266 -> bias, else 0.
// ---------------------------------------------------------------------------
__global__ __launch_bounds__(64) void build_wswz(
    const float* __restrict__ Wgx, const float* __restrict__ Wgh, const float* __restrict__ bg,
    const float* __restrict__ Wix, const float* __restrict__ Wih, const float* __restrict__ bi,
    const float* __restrict__ Wfx, const float* __restrict__ Wfh, const float* __restrict__ bf_,
    const float* __restrict__ Wox, const float* __restrict__ Woh, const float* __restrict__ bo,
    unsigned short* __restrict__ wswz)
{
    int g   = blockIdx.x / NKIT;   // ntile
    int kit = blockIdx.x % NKIT;
    int lane = threadIdx.x;
    int n = g * 16 + (lane & 15);
    int q = n >> 8;
    int col = n & 255;
    const float* Wh = (q == 0) ? Wgh : (q == 1) ? Wih : (q == 2) ? Wfh : Woh;
    const float* Wx = (q == 0) ? Wgx : (q == 1) ? Wix : (q == 2) ? Wfx : Wox;
    const float* bb = (q == 0) ? bg  : (q == 1) ? bi  : (q == 2) ? bf_ : bo;
    int k0 = kit * 32 + (lane >> 4) * 8;

    int4 out;
    unsigned short* p = (unsigned short*)&out;
#pragma unroll
    for (int j = 0; j < 8; j++) {
        int k = k0 + j;
        float v = 0.0f;
        if (k < 256)             v = Wh[k * 256 + col];
        else if (k < 256 + EMBD) v = Wx[(k - 256) * 256 + col];
        else if (k == 266)       v = bb[col];
        p[j] = f2bf(v);
    }
    ((int4*)wswz)[(kit * 64 + g) * 64 + lane] = out;
}

// ---------------------------------------------------------------------------
// K2: persistent LSTM. 64 blocks x 512 threads (8 waves), 1 block/CU.
// B-operand residency per CU: kits 0-3 + kit 8 in VGPRs (40 int4/wave),
// kits 4-5 in LDS (128 KB, loaded once), kits 6-7 streamed from L2 per step
// (128 KB/step, 32-reg landing buffer reissued kit6->kit7).
// A-tile (16x288 bf16, MFMA A-frag order) double-buffered in LDS -> ONE
// barrier per step. c,h state fp32 in registers.
// ---------------------------------------------------------------------------
__global__ __launch_bounds__(512, 2) void lstm_main(
    const int*   __restrict__ xtok,   // [1024][1][256]
    const float* __restrict__ emb,    // [32000][10]
    const float* __restrict__ Wph,    // [256][10]
    const float* __restrict__ bp,     // [10]
    const unsigned short* __restrict__ wswz,
    float* __restrict__ out)          // [1024][10]
{
    __shared__ __align__(16) unsigned short A_lds[2][NKIT * 64 * 8];  // 18 KB
    __shared__ __align__(16) int4 B_lds[2 * 64 * 64];                 // 128 KB (kits 4,5)
    __shared__ float outacc[MB * 10];

    const int tid  = threadIdx.x;
    const int w    = tid >> 6;        // wave 0..7
    const int lane = tid & 63;
    const int quad = lane >> 4;
    const int l15  = lane & 15;
    const int blk  = blockIdx.x;

    const int m_x = tid >> 4;         // x-gather: batch row 0..15 (tid<256)
    const int e_x = tid & 15;         // emb element (valid if <10)

    const int4* Bg = (const int4*)wswz;

    // --- prologue: LDS B-cache (kits 4,5), 8192 int4 across 512 threads ---
    for (int i = tid; i < 2 * 64 * 64; i += 512)
        B_lds[i] = Bg[4 * 64 * 64 + i];

    // --- prologue: register-resident B (kits 0..3 and kit 8) ---
    int4 breg[4][8];
#pragma unroll
    for (int k = 0; k < 4; k++)
#pragma unroll
        for (int idx = 0; idx < 8; idx++) {
            int nt = (idx >> 1) * 16 + w * 2 + (idx & 1);
            breg[k][idx] = Bg[(k * 64 + nt) * 64 + lane];
        }
    int4 bx[8];
#pragma unroll
    for (int idx = 0; idx < 8; idx++) {
        int nt = (idx >> 1) * 16 + w * 2 + (idx & 1);
        bx[idx] = Bg[(8 * 64 + nt) * 64 + lane];
    }

    // --- init A-tile double buffer: zero, bias row in BOTH, x_0 in buf0 ---
    for (int i = tid; i < NKIT * 64 * 8; i += 512) {
        A_lds[0][i] = 0; A_lds[1][i] = 0;
    }
    __syncthreads();
    if (tid < 16) {
        // k=266: kit=8, lp = m+16, j=2
        A_lds[0][(8 * 64 + 16 + tid) * 8 + 2] = 0x3F80;  // bf16(1.0)
        A_lds[1][(8 * 64 + 16 + tid) * 8 + 2] = 0x3F80;
    }
    if (tid < 256 && e_x < EMBD) {
        int tok = xtok[(blk * MB + m_x) * T_STEPS + 0];
        float v = emb[tok * EMBD + e_x];
        int k = 256 + e_x;
        int lp = m_x + 16 * ((k >> 3) & 3);
        A_lds[0][((k >> 5) * 64 + lp) * 8 + (k & 7)] = f2bf(v);
    }
    __syncthreads();

    float c[2][4], hreg[2][4];
#pragma unroll
    for (int u = 0; u < 2; u++)
#pragma unroll
        for (int r = 0; r < 4; r++) { c[u][r] = 0.0f; hreg[u][r] = 0.0f; }

    for (int t = 0; t < T_STEPS; t++) {
        const int4* Ab = (const int4*)A_lds[t & 1];
        unsigned short* Aw = A_lds[(t + 1) & 1];

        // stream kit 6 into landing regs (address-constant: issues early)
        int4 land[8];
#pragma unroll
        for (int idx = 0; idx < 8; idx++) {
            int nt = (idx >> 1) * 16 + w * 2 + (idx & 1);
            land[idx] = Bg[(6 * 64 + nt) * 64 + lane];
        }

        // x(t+1) prefetch
        float xval = 0.0f;
        const int do_x = (t < T_STEPS - 1) && (tid < 256) && (e_x < EMBD);
        if ((t < T_STEPS - 1) && (tid < 256)) {
            int tok = xtok[(blk * MB + m_x) * T_STEPS + (t + 1)];
            if (e_x < EMBD) xval = emb[tok * EMBD + e_x];
        }

        f32x4 acc[8];
#pragma unroll
        for (int i = 0; i < 8; i++) acc[i] = (f32x4){0.f, 0.f, 0.f, 0.f};

        // a-frag window (3 deep) over kit order: 0,1,2,3, 4,5, 6, 8, 7
        int4 a0 = Ab[0 * 64 + lane];
        int4 a1 = Ab[1 * 64 + lane];

        // kits 0..3 from registers
#pragma unroll
        for (int k = 0; k < 4; k++) {
            int4 ac = a0; a0 = a1; a1 = Ab[(k + 2) * 64 + lane];
#pragma unroll
            for (int idx = 0; idx < 8; idx++)
                acc[idx] = __builtin_amdgcn_mfma_f32_16x16x32_bf16(
                    __builtin_bit_cast(bf16x8, ac),
                    __builtin_bit_cast(bf16x8, breg[k][idx]), acc[idx], 0, 0, 0);
        }
        // kits 4,5 from LDS
#pragma unroll
        for (int k = 4; k < 6; k++) {
            int4 ac = a0; a0 = a1;
            a1 = Ab[((k == 4) ? 6 : 8) * 64 + lane];  // next a in order: 6 then 8
#pragma unroll
            for (int idx = 0; idx < 8; idx++) {
                int nt = (idx >> 1) * 16 + w * 2 + (idx & 1);
                acc[idx] = __builtin_amdgcn_mfma_f32_16x16x32_bf16(
                    __builtin_bit_cast(bf16x8, ac),
                    __builtin_bit_cast(bf16x8, B_lds[((k - 4) * 64 + nt) * 64 + lane]),
                    acc[idx], 0, 0, 0);
            }
        }
        // kit 6 from landing regs; reissue each slot with kit 7's frag
        {
            int4 ac = a0; a0 = a1; a1 = Ab[7 * 64 + lane];  // a for kit 7 (last)
#pragma unroll
            for (int idx = 0; idx < 8; idx++) {
                int nt = (idx >> 1) * 16 + w * 2 + (idx & 1);
                acc[idx] = __builtin_amdgcn_mfma_f32_16x16x32_bf16(
                    __builtin_bit_cast(bf16x8, ac),
                    __builtin_bit_cast(bf16x8, land[idx]), acc[idx], 0, 0, 0);
                land[idx] = Bg[(7 * 64 + nt) * 64 + lane];
            }
        }
        // kit 8 (x + bias) from registers; a0 holds A kit 8
        {
#pragma unroll
            for (int idx = 0; idx < 8; idx++)
                acc[idx] = __builtin_amdgcn_mfma_f32_16x16x32_bf16(
                    __builtin_bit_cast(bf16x8, a0),
                    __builtin_bit_cast(bf16x8, bx[idx]), acc[idx], 0, 0, 0);
        }
        // kit 7 from reissued landing regs
        {
#pragma unroll
            for (int idx = 0; idx < 8; idx++)
                acc[idx] = __builtin_amdgcn_mfma_f32_16x16x32_bf16(
                    __builtin_bit_cast(bf16x8, a1),
                    __builtin_bit_cast(bf16x8, land[idx]), acc[idx], 0, 0, 0);
        }

        // gates: z[m][n], m = quad*4 + r, n = gate*256 + w*32 + u*16 + l15
#pragma unroll
        for (int u = 0; u < 2; u++) {
#pragma unroll
            for (int r = 0; r < 4; r++) {
                float zg = acc[0 * 2 + u][r];
                float zi = acc[1 * 2 + u][r];
                float zf = acc[2 * 2 + u][r];
                float zo = acc[3 * 2 + u][r];
                float gg = tanh_fast(zg);
                float ii = sig_fast(zi);
                float ff = sig_fast(zf);
                float oo = sig_fast(zo);
                float cn = gg * ii + c[u][r] * ff;
                c[u][r] = cn;
                float hh = tanh_fast(cn) * oo;
                hreg[u][r] = hh;
                int m = quad * 4 + r;
                int hcol = w * 32 + u * 16 + l15;
                int lp = m + 16 * ((hcol >> 3) & 3);
                Aw[(w * 64 + lp) * 8 + (hcol & 7)] = f2bf(hh);
            }
        }
        if (do_x) {
            int k = 256 + e_x;
            int lp = m_x + 16 * ((k >> 3) & 3);
            Aw[(8 * 64 + lp) * 8 + (k & 7)] = f2bf(xval);
        }
        __syncthreads();  // single barrier: A(t+1) complete, all read A(t)
    }

    // --- epilogue: out[m][cls] = sum_hcol h[m][hcol]*Wph[hcol][cls] + bp ---
    float part[4][10];
#pragma unroll
    for (int r = 0; r < 4; r++)
#pragma unroll
        for (int cl = 0; cl < 10; cl++) part[r][cl] = 0.0f;
#pragma unroll
    for (int u = 0; u < 2; u++) {
        int hcol = w * 32 + u * 16 + l15;
#pragma unroll
        for (int cl = 0; cl < 10; cl++) {
            float wv = Wph[hcol * 10 + cl];
#pragma unroll
            for (int r = 0; r < 4; r++) part[r][cl] += hreg[u][r] * wv;
        }
    }
#pragma unroll
    for (int off = 1; off < 16; off <<= 1) {
#pragma unroll
        for (int r = 0; r < 4; r++)
#pragma unroll
            for (int cl = 0; cl < 10; cl++)
                part[r][cl] += __shfl_xor(part[r][cl], off, 64);
    }
    if (tid < MB * 10) outacc[tid] = 0.0f;
    __syncthreads();
    if (l15 == 0) {
#pragma unroll
        for (int r = 0; r < 4; r++) {
            int m = quad * 4 + r;
#pragma unroll
            for (int cl = 0; cl < 10; cl++)
                atomicAdd(&outacc[m * 10 + cl], part[r][cl]);
        }
    }
    __syncthreads();
    if (tid < MB * 10) {
        int m = tid / 10, cl = tid - m * 10;
        out[(blk * MB + m) * 10 + cl] = outacc[tid] + bp[cl];
    }
}

extern "C" void kernel_launch(void* const* d_in, const int* in_sizes, int n_in,
                              void* d_out, int out_size, void* d_ws, size_t ws_size,
                              hipStream_t stream) {
    const int*   x    = (const int*)  d_in[0];
    const float* emb  = (const float*)d_in[1];
    const float* Wgx  = (const float*)d_in[2];
    const float* Wgh  = (const float*)d_in[3];
    const float* bg   = (const float*)d_in[4];
    const float* Wix  = (const float*)d_in[5];
    const float* Wih  = (const float*)d_in[6];
    const float* bi   = (const float*)d_in[7];
    const float* Wfx  = (const float*)d_in[8];
    const float* Wfh  = (const float*)d_in[9];
    const float* bf_  = (const float*)d_in[10];
    const float* Wox  = (const float*)d_in[11];
    const float* Woh  = (const float*)d_in[12];
    const float* bo   = (const float*)d_in[13];
    const float* Wph  = (const float*)d_in[14];
    const float* bp   = (const float*)d_in[15];

    unsigned short* wswz = (unsigned short*)d_ws;  // 9*64*64*16 = 576 KB

    build_wswz<<<NBLK * NKIT, 64, 0, stream>>>(Wgx, Wgh, bg, Wix, Wih, bi,
                                               Wfx, Wfh, bf_, Wox, Woh, bo, wswz);
    lstm_main<<<NBLK, 512, 0, stream>>>(x, emb, Wph, bp, wswz, (float*)d_out);
}